// Round 1
// baseline (31.419 us; speedup 1.0000x reference)
//
#include <hip/hip_runtime.h>
#include <math.h>

#define SOFT_W 0.5f
#define LSM 0.1f

// Kernel 1: one block per (b,t) token. Streams the V-length row of logits and
// soft_labels once (float4, coalesced), computing online max/sum-exp, sum(x),
// sum(x*w), sum(w). Writes masked per-token partials (soft_tok, hard_tok) to ws.
__global__ __launch_bounds__(256) void distill_token_kernel(
    const float* __restrict__ logits,
    const int*   __restrict__ ys,
    const float* __restrict__ soft,
    const int*   __restrict__ ylens,
    float* __restrict__ ws,
    int B, int T, int V)
{
    const int token = blockIdx.x;
    const int nTok  = B * T;
    const int b = token / T;
    const int t = token - b * T;

    if (t >= ylens[b]) {
        if (threadIdx.x == 0) { ws[token] = 0.0f; ws[nTok + token] = 0.0f; }
        return;
    }

    const size_t rowOff = (size_t)token * (size_t)V;
    const float4* lg4 = (const float4*)(logits + rowOff);
    const float4* sl4 = (const float4*)(soft   + rowOff);
    const int n4 = V >> 2;

    float m = -INFINITY;   // running max
    float s = 0.0f;        // running sum exp(x - m)
    float sumx  = 0.0f;    // sum of logits
    float sumxs = 0.0f;    // sum logits * soft
    float sumsl = 0.0f;    // sum soft (≈1, used exactly)

    for (int i = threadIdx.x; i < n4; i += blockDim.x) {
        float4 x = lg4[i];
        float4 w = sl4[i];
        sumx  += (x.x + x.y) + (x.z + x.w);
        sumsl += (w.x + w.y) + (w.z + w.w);
        sumxs += x.x * w.x + x.y * w.y + x.z * w.z + x.w * w.w;
        float xm = fmaxf(fmaxf(x.x, x.y), fmaxf(x.z, x.w));
        float nm = fmaxf(m, xm);
        s = s * __expf(m - nm)
          + (__expf(x.x - nm) + __expf(x.y - nm))
          + (__expf(x.z - nm) + __expf(x.w - nm));
        m = nm;
    }
    // scalar tail (V not multiple of 4 — not hit for V=10000, safety only)
    for (int i = (n4 << 2) + threadIdx.x; i < V; i += blockDim.x) {
        float x = logits[rowOff + i];
        float w = soft[rowOff + i];
        sumx += x; sumsl += w; sumxs += x * w;
        float nm = fmaxf(m, x);
        s = s * __expf(m - nm) + __expf(x - nm);
        m = nm;
    }

    // wave (64-lane) butterfly reduction
    #pragma unroll
    for (int off = 32; off > 0; off >>= 1) {
        float om = __shfl_xor(m, off, 64);
        float os = __shfl_xor(s, off, 64);
        float nm = fmaxf(m, om);
        s = s * __expf(m - nm) + os * __expf(om - nm);
        m = nm;
        sumx  += __shfl_xor(sumx,  off, 64);
        sumxs += __shfl_xor(sumxs, off, 64);
        sumsl += __shfl_xor(sumsl, off, 64);
    }

    __shared__ float sm[4], ss[4], sx[4], sxs[4], ssl[4];
    const int wid  = threadIdx.x >> 6;
    const int lane = threadIdx.x & 63;
    if (lane == 0) { sm[wid] = m; ss[wid] = s; sx[wid] = sumx; sxs[wid] = sumxs; ssl[wid] = sumsl; }
    __syncthreads();

    if (threadIdx.x == 0) {
        m = sm[0]; s = ss[0]; sumx = sx[0]; sumxs = sxs[0]; sumsl = ssl[0];
        const int nw = (blockDim.x + 63) >> 6;
        for (int w = 1; w < nw; ++w) {
            float om = sm[w], os = ss[w];
            float nm = fmaxf(m, om);
            s = s * __expf(m - nm) + os * __expf(om - nm);
            m = nm;
            sumx += sx[w]; sumxs += sxs[w]; sumsl += ssl[w];
        }
        const float lse = m + logf(s);

        const int y = ys[token];
        const float xy = logits[rowOff + (size_t)y];
        const float lp_y   = xy - lse;
        const float lp_sum = sumx - (float)V * lse;
        const float soft_tok = sumxs - lse * sumsl;
        const float hard_tok = (1.0f - LSM) * lp_y
                             + (LSM / (float)(V - 1)) * (lp_sum - lp_y);
        ws[token]        = soft_tok;
        ws[nTok + token] = hard_tok;
    }
}

// Kernel 2: single-block deterministic reduction of per-token partials → 3 scalars.
__global__ __launch_bounds__(256) void distill_reduce_kernel(
    const float* __restrict__ ws, float* __restrict__ out, int nTok, float invB)
{
    float s1 = 0.0f, s2 = 0.0f;
    for (int i = threadIdx.x; i < nTok; i += blockDim.x) {
        s1 += ws[i];
        s2 += ws[nTok + i];
    }
    #pragma unroll
    for (int off = 32; off > 0; off >>= 1) {
        s1 += __shfl_xor(s1, off, 64);
        s2 += __shfl_xor(s2, off, 64);
    }
    __shared__ float a1[4], a2[4];
    const int wid  = threadIdx.x >> 6;
    const int lane = threadIdx.x & 63;
    if (lane == 0) { a1[wid] = s1; a2[wid] = s2; }
    __syncthreads();
    if (threadIdx.x == 0) {
        float S1 = (a1[0] + a1[1]) + (a1[2] + a1[3]);
        float S2 = (a2[0] + a2[1]) + (a2[2] + a2[3]);
        float loss_soft = -S1 * invB;
        float loss_hard = -S2 * invB;
        out[0] = SOFT_W * loss_soft + (1.0f - SOFT_W) * loss_hard;
        out[1] = loss_soft;
        out[2] = loss_hard;
    }
}

extern "C" void kernel_launch(void* const* d_in, const int* in_sizes, int n_in,
                              void* d_out, int out_size, void* d_ws, size_t ws_size,
                              hipStream_t stream) {
    const float* logits = (const float*)d_in[0];
    const int*   ys     = (const int*)d_in[1];
    const float* soft   = (const float*)d_in[2];
    const int*   ylens  = (const int*)d_in[3];
    float* out = (float*)d_out;
    float* ws  = (float*)d_ws;

    const int B    = in_sizes[3];
    const int nTok = in_sizes[1];          // B*T
    const int T    = nTok / B;
    const int V    = in_sizes[0] / nTok;

    distill_token_kernel<<<nTok, 256, 0, stream>>>(logits, ys, soft, ylens, ws, B, T, V);
    distill_reduce_kernel<<<1, 256, 0, stream>>>(ws, out, nTok, 1.0f / (float)B);
}

// Round 2
// 30.340 us; speedup vs baseline: 1.0356x; 1.0356x over previous
//
#include <hip/hip_runtime.h>
#include <math.h>

#define SOFT_W 0.5f
#define LSM 0.1f

// Kernel 1: one block per (b,t) token, grid = (T, B). Streams the V-length row
// of logits and soft_labels once (float4, coalesced). Two independent online
// max/sum-exp accumulator sets (A/B) break the serial rescale chain and let the
// compiler batch 4x16B loads per iteration. Writes per-token (soft_tok,
// hard_tok) partials as float2 to ws; masked tokens write zeros.
__global__ __launch_bounds__(256) void distill_token_kernel(
    const float* __restrict__ logits,
    const int*   __restrict__ ys,
    const float* __restrict__ soft,
    const int*   __restrict__ ylens,
    float2* __restrict__ ws,
    int T, int V)
{
    const int t = blockIdx.x;
    const int b = blockIdx.y;
    const int token = b * T + t;

    if (t >= ylens[b]) {
        if (threadIdx.x == 0) ws[token] = make_float2(0.0f, 0.0f);
        return;
    }

    const size_t rowOff = (size_t)token * (size_t)V;
    const float4* lg4 = (const float4*)(logits + rowOff);
    const float4* sl4 = (const float4*)(soft   + rowOff);
    const int n4 = V >> 2;   // V assumed multiple of 4 (10000)

    // accumulator set A
    float mA = -INFINITY, sA = 0.0f;
    // accumulator set B
    float mB = -INFINITY, sB = 0.0f;
    float sumx = 0.0f, sumxs = 0.0f, sumsl = 0.0f;

    int i = threadIdx.x;
    for (; i + 256 < n4; i += 512) {
        float4 xa = lg4[i];
        float4 wa = sl4[i];
        float4 xb = lg4[i + 256];
        float4 wb = sl4[i + 256];

        sumx  += ((xa.x + xa.y) + (xa.z + xa.w)) + ((xb.x + xb.y) + (xb.z + xb.w));
        sumsl += ((wa.x + wa.y) + (wa.z + wa.w)) + ((wb.x + wb.y) + (wb.z + wb.w));
        sumxs += xa.x * wa.x + xa.y * wa.y + xa.z * wa.z + xa.w * wa.w
               + xb.x * wb.x + xb.y * wb.y + xb.z * wb.z + xb.w * wb.w;

        float xmA = fmaxf(fmaxf(xa.x, xa.y), fmaxf(xa.z, xa.w));
        float nmA = fmaxf(mA, xmA);
        sA = sA * __expf(mA - nmA)
           + (__expf(xa.x - nmA) + __expf(xa.y - nmA))
           + (__expf(xa.z - nmA) + __expf(xa.w - nmA));
        mA = nmA;

        float xmB = fmaxf(fmaxf(xb.x, xb.y), fmaxf(xb.z, xb.w));
        float nmB = fmaxf(mB, xmB);
        sB = sB * __expf(mB - nmB)
           + (__expf(xb.x - nmB) + __expf(xb.y - nmB))
           + (__expf(xb.z - nmB) + __expf(xb.w - nmB));
        mB = nmB;
    }
    if (i < n4) {
        float4 xa = lg4[i];
        float4 wa = sl4[i];
        sumx  += (xa.x + xa.y) + (xa.z + xa.w);
        sumsl += (wa.x + wa.y) + (wa.z + wa.w);
        sumxs += xa.x * wa.x + xa.y * wa.y + xa.z * wa.z + xa.w * wa.w;
        float xmA = fmaxf(fmaxf(xa.x, xa.y), fmaxf(xa.z, xa.w));
        float nmA = fmaxf(mA, xmA);
        sA = sA * __expf(mA - nmA)
           + (__expf(xa.x - nmA) + __expf(xa.y - nmA))
           + (__expf(xa.z - nmA) + __expf(xa.w - nmA));
        mA = nmA;
    }

    // merge A/B
    float m = fmaxf(mA, mB);
    float s = sA * __expf(mA - m) + sB * __expf(mB - m);

    // wave (64-lane) butterfly reduction
    #pragma unroll
    for (int off = 32; off > 0; off >>= 1) {
        float om = __shfl_xor(m, off, 64);
        float os = __shfl_xor(s, off, 64);
        float nm = fmaxf(m, om);
        s = s * __expf(m - nm) + os * __expf(om - nm);
        m = nm;
        sumx  += __shfl_xor(sumx,  off, 64);
        sumxs += __shfl_xor(sumxs, off, 64);
        sumsl += __shfl_xor(sumsl, off, 64);
    }

    __shared__ float sm[4], ss[4], sx[4], sxs[4], ssl[4];
    const int wid  = threadIdx.x >> 6;
    const int lane = threadIdx.x & 63;
    if (lane == 0) { sm[wid] = m; ss[wid] = s; sx[wid] = sumx; sxs[wid] = sumxs; ssl[wid] = sumsl; }
    __syncthreads();

    if (threadIdx.x == 0) {
        m = sm[0]; s = ss[0]; sumx = sx[0]; sumxs = sxs[0]; sumsl = ssl[0];
        #pragma unroll
        for (int w = 1; w < 4; ++w) {
            float om = sm[w], os = ss[w];
            float nm = fmaxf(m, om);
            s = s * __expf(m - nm) + os * __expf(om - nm);
            m = nm;
            sumx += sx[w]; sumxs += sxs[w]; sumsl += ssl[w];
        }
        const float lse = m + logf(s);

        const int y = ys[token];
        const float xy = logits[rowOff + (size_t)y];   // L2-hot: row just streamed
        const float lp_y   = xy - lse;
        const float lp_sum = sumx - (float)V * lse;
        const float soft_tok = sumxs - lse * sumsl;
        const float hard_tok = (1.0f - LSM) * lp_y
                             + (LSM / (float)(V - 1)) * (lp_sum - lp_y);
        ws[token] = make_float2(soft_tok, hard_tok);
    }
}

// Kernel 2: single-block deterministic reduction of per-token float2 partials.
__global__ __launch_bounds__(256) void distill_reduce_kernel(
    const float2* __restrict__ ws, float* __restrict__ out, int nTok, float invB)
{
    float s1 = 0.0f, s2 = 0.0f;
    for (int i = threadIdx.x; i < nTok; i += blockDim.x) {
        float2 p = ws[i];
        s1 += p.x;
        s2 += p.y;
    }
    #pragma unroll
    for (int off = 32; off > 0; off >>= 1) {
        s1 += __shfl_xor(s1, off, 64);
        s2 += __shfl_xor(s2, off, 64);
    }
    __shared__ float a1[4], a2[4];
    const int wid  = threadIdx.x >> 6;
    const int lane = threadIdx.x & 63;
    if (lane == 0) { a1[wid] = s1; a2[wid] = s2; }
    __syncthreads();
    if (threadIdx.x == 0) {
        float S1 = (a1[0] + a1[1]) + (a1[2] + a1[3]);
        float S2 = (a2[0] + a2[1]) + (a2[2] + a2[3]);
        float loss_soft = -S1 * invB;
        float loss_hard = -S2 * invB;
        out[0] = SOFT_W * loss_soft + (1.0f - SOFT_W) * loss_hard;
        out[1] = loss_soft;
        out[2] = loss_hard;
    }
}

extern "C" void kernel_launch(void* const* d_in, const int* in_sizes, int n_in,
                              void* d_out, int out_size, void* d_ws, size_t ws_size,
                              hipStream_t stream) {
    const float* logits = (const float*)d_in[0];
    const int*   ys     = (const int*)d_in[1];
    const float* soft   = (const float*)d_in[2];
    const int*   ylens  = (const int*)d_in[3];
    float* out = (float*)d_out;
    float2* ws = (float2*)d_ws;

    const int B    = in_sizes[3];
    const int nTok = in_sizes[1];          // B*T
    const int T    = nTok / B;
    const int V    = in_sizes[0] / nTok;

    dim3 grid(T, B);
    distill_token_kernel<<<grid, 256, 0, stream>>>(logits, ys, soft, ylens, ws, T, V);
    distill_reduce_kernel<<<1, 256, 0, stream>>>(ws, out, nTok, 1.0f / (float)B);
}